// Round 6
// baseline (249.763 us; speedup 1.0000x reference)
//
#include <hip/hip_runtime.h>

// IDWT reconstruction — persistent XCD-chunked sweep.
// x: (B=16, L=32768, 64) f32, [0,32)=A, [32,64)=D. out: (16, 2L, 32).
// out[b, 2p,   c] = sum_t lo[2t+1]*A[p-1+t][c] + hi[2t+1]*D[p-1+t][c]
// out[b, 2p+1, c] = sum_t lo[2t  ]*A[p-1+t][c] + hi[2t  ]*D[p-1+t][c]
//
// Evidence so far: 4 structures (naive / reg-tiled / parity-dense /
// LDS-staged) all ~67-85 us with VALU<9%, HBM ~31%, occ 33-70% -> no
// CU-side resource binds; memory system delivers only ~2.5-3.3 TB/s.
// Last variable: DRAM-side stream locality. 2048 persistent WGs,
// bijectively remapped so each XCD sweeps a CONTIGUOUS 1/8 slab
// (reads and writes), 16 work-items per thread for cross-iter MLP.

#define B_    16
#define L_    32768
#define CIN_  64
#define COUT_ 32
#define NBLK  2048
#define PPB   256      // contiguous p-positions per block (256 | 32768: no batch straddle)
#define ITERS 16       // PPB / (256 threads / 16 threads-per-p)

typedef float vfloat4 __attribute__((ext_vector_type(4)));

__global__ __launch_bounds__(256) void idwt_kernel(
    const float* __restrict__ x,
    const float* __restrict__ rec_lo,
    const float* __restrict__ rec_hi,
    float* __restrict__ out)
{
    // XCD-chunked bijective remap (NBLK % 8 == 0): blocks on XCD k own
    // the contiguous slab [k*256, (k+1)*256) of block-indices.
    const int bb = (blockIdx.x & 7) * (NBLK / 8) + (blockIdx.x >> 3);

    const int t_     = threadIdx.x;
    const int g      = t_ & 7;          // float4 channel group
    const int parity = (t_ >> 3) & 1;   // 0: even output row (loads A), 1: odd (loads D)
    const int pg     = t_ >> 4;         // 0..15: p within a wave-pass

    const int pbase = bb * PPB;         // global p of block start
    const int b     = pbase >> 15;      // batch (constant per block)
    const int pb    = pbase & (L_ - 1);

    // my half: parity 0 -> A at +0, parity 1 -> D at +32 floats
    const float* xb = x + (size_t)b * (L_ * CIN_) + (g << 2) + (parity ? COUT_ : 0);
    float*       ob = out + ((size_t)b * (2 * L_) + parity) * COUT_ + (g << 2);

    // taps: even rows use {lo,hi}[2t+1] on (A,D); odd rows {lo,hi}[2t].
    // fm applies to my-loaded half, fo to the shfl-received half.
    float fm[4], fo[4];
#pragma unroll
    for (int t = 0; t < 4; ++t) {
        fm[t] = parity ? rec_hi[2 * t] : rec_lo[2 * t + 1];
        fo[t] = parity ? rec_lo[2 * t] : rec_hi[2 * t + 1];
    }

#pragma unroll 2
    for (int it = 0; it < ITERS; ++it) {
        const int p = pb + it * 16 + pg;

        // Load my 4 rows (one half each). Wave-level: fully dense 1 KB
        // per load inst (lanes 0-7 A-chunk, 8-15 adjacent D-chunk, ...).
        float m[4][4];
#pragma unroll
        for (int t = 0; t < 4; ++t) {
            const int j = p - 1 + t;
            vfloat4 v = {0.f, 0.f, 0.f, 0.f};
            if ((unsigned)j < (unsigned)L_)
                v = *(const vfloat4*)(xb + (size_t)j * CIN_);
            m[t][0] = v.x; m[t][1] = v.y; m[t][2] = v.z; m[t][3] = v.w;
        }

        // Partner lane (^8) holds the other half for the same p.
        float o_[4][4];
#pragma unroll
        for (int t = 0; t < 4; ++t)
#pragma unroll
            for (int c = 0; c < 4; ++c)
                o_[t][c] = __shfl_xor(m[t][c], 8, 64);

        float acc[4] = {0.f, 0.f, 0.f, 0.f};
#pragma unroll
        for (int t = 0; t < 4; ++t)
#pragma unroll
            for (int c = 0; c < 4; ++c)
                acc[c] = fmaf(fm[t], m[t][c], fmaf(fo[t], o_[t][c], acc[c]));

        // Dense wave-level 1 KB store; output never re-read.
        vfloat4 v = {acc[0], acc[1], acc[2], acc[3]};
        __builtin_nontemporal_store(v, (vfloat4*)(ob + (size_t)(2 * p) * COUT_));
    }
}

extern "C" void kernel_launch(void* const* d_in, const int* in_sizes, int n_in,
                              void* d_out, int out_size, void* d_ws, size_t ws_size,
                              hipStream_t stream) {
    const float* x      = (const float*)d_in[0];
    const float* rec_lo = (const float*)d_in[1];
    const float* rec_hi = (const float*)d_in[2];
    float* out = (float*)d_out;

    idwt_kernel<<<NBLK, 256, 0, stream>>>(x, rec_lo, rec_hi, out);
}

// Round 7
// 228.007 us; speedup vs baseline: 1.0954x; 1.0954x over previous
//
#include <hip/hip_runtime.h>

// IDWT reconstruction, parity-split lanes + A/D lane-split loads.
// x: (B=16, L=32768, 64) f32, channels [0,32)=approx A, [32,64)=detail D.
// out: (16, 2L, 32) f32.
//
// out[b, 2p,   c] = sum_t lo[2t+1]*A[p-1+t][c] + hi[2t+1]*D[p-1+t][c]
// out[b, 2p+1, c] = sum_t lo[2t  ]*A[p-1+t][c] + hi[2t  ]*D[p-1+t][c]
//
// Thread = (b, p, parity, c4). parity 0 -> even row, loads A-half only;
// parity 1 -> odd row, loads D-half only. Halves exchanged via
// __shfl_xor(lane^8). Wave-level loads AND stores are fully dense 1 KB.
// 5 VMEM / thread; 8.4M threads / 32768 WGs.
//
// SESSION RECORD (6 structural variants): this and the naive dense
// version tie at total 226.87/226.91 us (kernel ~65-70 us). PT-tiling,
// LDS staging, persistence, and XCD-chunking all regressed or were
// neutral; all CU-side counters idle (VALU<=11%, conflicts 0, occ
// uncorrelated). Kernel is bound by delivered mixed-stream memory
// bandwidth (~3.3-4 TB/s for this pattern), not by any CU resource.

#define B_    16
#define L_    32768
#define CIN_  64
#define COUT_ 32

typedef float vfloat4 __attribute__((ext_vector_type(4)));

__global__ __launch_bounds__(256) void idwt_kernel(
    const float* __restrict__ x,
    const float* __restrict__ rec_lo,
    const float* __restrict__ rec_hi,
    float* __restrict__ out)
{
    const int tid    = blockIdx.x * blockDim.x + threadIdx.x;
    const int g      = tid & 7;          // float4 channel group
    const int parity = (tid >> 3) & 1;   // 0: even output row, 1: odd
    const int pp     = tid >> 4;         // (b, p)
    const int p      = pp & (L_ - 1);
    const int b      = pp >> 15;         // L_ = 2^15

    // my half: parity 0 -> A at +0, parity 1 -> D at +32 floats
    const float* xb = x + b * (L_ * CIN_) + (g << 2) + (parity ? COUT_ : 0);

    // Load my 4 rows (16 floats). Wave: fully dense 1KB per load instr.
    float m[4][4];
#pragma unroll
    for (int t = 0; t < 4; ++t) {
        const int j = p - 1 + t;
        if ((unsigned)j < (unsigned)L_) {
            const vfloat4 v = *(const vfloat4*)(xb + j * CIN_);
            m[t][0] = v.x; m[t][1] = v.y; m[t][2] = v.z; m[t][3] = v.w;
        } else {
            m[t][0] = 0.f; m[t][1] = 0.f; m[t][2] = 0.f; m[t][3] = 0.f;
        }
    }

    // Exchange halves with the partner lane (lane ^ 8): I get the other
    // half's 16 floats. VALU/LDS pipes are idle; this is free.
    float o_[4][4];
#pragma unroll
    for (int t = 0; t < 4; ++t)
#pragma unroll
        for (int c = 0; c < 4; ++c)
            o_[t][c] = __shfl_xor(m[t][c], 8, 64);

    // Filter coefficients applied to my-loaded half (fm) and received
    // half (fo):
    //   parity 0: m=A -> fm[t]=lo[2t+1], o_=D -> fo[t]=hi[2t+1]
    //   parity 1: m=D -> fm[t]=hi[2t],   o_=A -> fo[t]=lo[2t]
    float fm[4], fo[4];
#pragma unroll
    for (int t = 0; t < 4; ++t) {
        fm[t] = parity ? rec_hi[2 * t]     : rec_lo[2 * t + 1];
        fo[t] = parity ? rec_lo[2 * t]     : rec_hi[2 * t + 1];
    }

    float acc[4] = {0.f, 0.f, 0.f, 0.f};
#pragma unroll
    for (int t = 0; t < 4; ++t)
#pragma unroll
        for (int c = 0; c < 4; ++c)
            acc[c] = fmaf(fm[t], m[t][c], fmaf(fo[t], o_[t][c], acc[c]));

    // Store one float4. Wave: fully dense 1KB (g fastest, then parity
    // = adjacent row, then p = next row-pair).
    float* orow = out + (b * (2 * L_) + 2 * p + parity) * COUT_ + (g << 2);
    vfloat4 v = { acc[0], acc[1], acc[2], acc[3] };
    __builtin_nontemporal_store(v, (vfloat4*)orow);
}

extern "C" void kernel_launch(void* const* d_in, const int* in_sizes, int n_in,
                              void* d_out, int out_size, void* d_ws, size_t ws_size,
                              hipStream_t stream) {
    const float* x      = (const float*)d_in[0];
    const float* rec_lo = (const float*)d_in[1];
    const float* rec_hi = (const float*)d_in[2];
    float* out = (float*)d_out;

    const int total_threads = B_ * L_ * 2 * (COUT_ / 4); // 8,388,608
    const int block = 256;
    idwt_kernel<<<total_threads / block, block, 0, stream>>>(x, rec_lo, rec_hi, out);
}